// Round 2
// baseline (5400.599 us; speedup 1.0000x reference)
//
#include <hip/hip_runtime.h>
#include <math.h>

// KMeansGrouping: B=32, N=4096, D=256, K=24, 25 iters.
// Hybrid precision: distance/argmin in f32 (perturbs scores ~1e-6, vs the
// ~1e-4 ours-vs-f32-ref divergence already tolerated in round 1), center
// updates + reductions in f64 with the exact same deterministic order as the
// verified-passing round-1 kernel.
// Phase 1: 2 points/thread x half-D/thread -> 768 broadcast ds_read_b128 per
// thread (8 f32 FMA per read), 2048 waves total (8 waves/CU).

#define BATCH 32
#define NPTS 4096
#define DIM 256
#define NSLOT 24
#define NITER 25
#define NCHUNK 16
#define PTS 256 // points per block

// ---------------- K0: per-point inverse norm (f64) ----------------
__global__ __launch_bounds__(256) void k_norm(const float* __restrict__ feat,
                                              double* __restrict__ inv_norm) {
  int lane = threadIdx.x & 63;
  int wid = threadIdx.x >> 6;
  int p = blockIdx.x * 4 + wid; // one wave per point
  const float4 v = *(const float4*)(feat + (size_t)p * DIM + lane * 4);
  double s = (double)v.x * v.x + (double)v.y * v.y + (double)v.z * v.z + (double)v.w * v.w;
#pragma unroll
  for (int m = 32; m; m >>= 1) s += __shfl_xor(s, m);
  if (lane == 0) inv_norm[p] = 1.0 / fmax(sqrt(s), 1e-12);
}

__device__ __forceinline__ double block_sum_256(double v, double* red) {
#pragma unroll
  for (int m = 32; m; m >>= 1) v += __shfl_xor(v, m);
  int w = threadIdx.x >> 6;
  if ((threadIdx.x & 63) == 0) red[w] = v;
  __syncthreads();
  return red[0] + red[1] + red[2] + red[3];
}

// ---------------- K0b: initial centers (f64 + f32 copy) + c_sq (f32) -------
__global__ __launch_bounds__(256) void k_init_centers(const float* __restrict__ feat,
                                                      const double* __restrict__ inv_norm,
                                                      double* __restrict__ centers,
                                                      float* __restrict__ centers_f32,
                                                      float* __restrict__ c_sq_f32) {
  __shared__ double red[4];
  int t = threadIdx.x, k = blockIdx.x, b = blockIdx.y;
  int idx = (int)((double)k * (NPTS - 1) / (NSLOT - 1)); // numpy linspace floor
  double v = (double)feat[((size_t)b * NPTS + idx) * DIM + t] * inv_norm[b * NPTS + idx];
  size_t ci = ((size_t)b * NSLOT + k) * DIM + t;
  centers[ci] = v;
  centers_f32[ci] = (float)v;
  double s = block_sum_256(v * v, red);
  if (t == 0) c_sq_f32[b * NSLOT + k] = (float)s;
}

// ---------------- K1: fused assign (f32) + partial center sums (f64) -------
#define CASE_ACC(i) \
  case i: acc[i] += xv; ++cnt[i]; break;

__global__ __launch_bounds__(256, 2) void k_iter(const float* __restrict__ feat,
                                                 const double* __restrict__ inv_norm,
                                                 const double* __restrict__ centers,
                                                 const float* __restrict__ centers_f32,
                                                 const float* __restrict__ c_sq_f32,
                                                 double* __restrict__ psums,
                                                 int* __restrict__ pcnts,
                                                 float* __restrict__ masks_out,
                                                 float* __restrict__ centers_out,
                                                 int final_pass) {
  __shared__ float c_lds[NSLOT * DIM];        // 24 KB
  __shared__ float part[128][2 * NSLOT + 1];  // 25088 B, +1 pad breaks bank conflicts
  __shared__ float csq_lds[NSLOT];
  __shared__ int assign_lds[PTS];
  int t = threadIdx.x, ch = blockIdx.x, b = blockIdx.y;

  const float* cf = centers_f32 + (size_t)b * NSLOT * DIM;
#pragma unroll
  for (int i = 0; i < NSLOT; ++i) c_lds[i * DIM + t] = cf[i * DIM + t];
  if (t < NSLOT) csq_lds[t] = c_sq_f32[b * NSLOT + t];
  __syncthreads();

  // ---- phase 1: 2 points/thread, half-D/thread, f32 ----
  int i = t & 127, h = t >> 7; // h uniform per wave (waves are 64-aligned)
  int p0 = ch * PTS + i * 2;
  const float* xp = feat + ((size_t)(b * NPTS + p0)) * DIM + h * 128;

  float dotA[NSLOT], dotB[NSLOT];
#pragma unroll
  for (int k = 0; k < NSLOT; ++k) { dotA[k] = 0.0f; dotB[k] = 0.0f; }

  for (int db = 0; db < 4; ++db) { // 4 blocks of 32 dims (of this half)
    float xa[32], xb[32];
#pragma unroll
    for (int j = 0; j < 8; ++j) {
      float4 v = *(const float4*)(xp + db * 32 + j * 4);
      xa[j * 4 + 0] = v.x; xa[j * 4 + 1] = v.y; xa[j * 4 + 2] = v.z; xa[j * 4 + 3] = v.w;
      float4 w = *(const float4*)(xp + DIM + db * 32 + j * 4);
      xb[j * 4 + 0] = w.x; xb[j * 4 + 1] = w.y; xb[j * 4 + 2] = w.z; xb[j * 4 + 3] = w.w;
    }
#pragma unroll
    for (int k = 0; k < NSLOT; ++k) {
      const float* cp = &c_lds[k * DIM + h * 128 + db * 32]; // wave-uniform -> broadcast
      float sA = dotA[k], sB = dotB[k];
#pragma unroll
      for (int j = 0; j < 32; j += 4) {
        float4 cv = *(const float4*)(cp + j);
        sA += xa[j + 0] * cv.x; sB += xb[j + 0] * cv.x;
        sA += xa[j + 1] * cv.y; sB += xb[j + 1] * cv.y;
        sA += xa[j + 2] * cv.z; sB += xb[j + 2] * cv.z;
        sA += xa[j + 3] * cv.w; sB += xb[j + 3] * cv.w;
      }
      dotA[k] = sA; dotB[k] = sB;
    }
  }

  if (h == 1) {
#pragma unroll
    for (int k = 0; k < NSLOT; ++k) { part[i][k] = dotA[k]; part[i][NSLOT + k] = dotB[k]; }
  }
  __syncthreads();

  int a0 = 0, a1 = 0;
  if (h == 0) {
    float inv0 = (float)inv_norm[b * NPTS + p0];
    float inv1 = (float)inv_norm[b * NPTS + p0 + 1];
    float best0 = csq_lds[0] - 2.0f * ((dotA[0] + part[i][0]) * inv0);
    float best1 = csq_lds[0] - 2.0f * ((dotB[0] + part[i][NSLOT]) * inv1);
#pragma unroll
    for (int k = 1; k < NSLOT; ++k) {
      float s0 = csq_lds[k] - 2.0f * ((dotA[k] + part[i][k]) * inv0);
      float s1 = csq_lds[k] - 2.0f * ((dotB[k] + part[i][NSLOT + k]) * inv1);
      if (s0 < best0) { best0 = s0; a0 = k; } // strict < = first-occurrence argmin
      if (s1 < best1) { best1 = s1; a1 = k; }
    }
    assign_lds[i * 2] = a0;
    assign_lds[i * 2 + 1] = a1;
  }

  if (final_pass) {
    if (h == 0) {
#pragma unroll
      for (int k = 0; k < NSLOT; ++k) {
        float2 m;
        m.x = (k == a0) ? 1.0f : 0.0f;
        m.y = (k == a1) ? 1.0f : 0.0f;
        *(float2*)(masks_out + ((size_t)b * NSLOT + k) * NPTS + p0) = m;
      }
    }
    if (ch == 0) {
      const double* cb = centers + (size_t)b * NSLOT * DIM;
#pragma unroll
      for (int k = 0; k < NSLOT; ++k)
        centers_out[((size_t)b * NSLOT + k) * DIM + t] = (float)cb[k * DIM + t];
    }
    return;
  }
  __syncthreads();

  // ---- phase 2: thread-per-dim f64 partial sums, identical order to round 1 ----
  double acc[NSLOT];
  int cnt[NSLOT];
#pragma unroll
  for (int k = 0; k < NSLOT; ++k) { acc[k] = 0.0; cnt[k] = 0; }

  const float* fb = feat + ((size_t)(b * NPTS + ch * PTS)) * DIM + t;
  const double* ib = inv_norm + b * NPTS + ch * PTS;
  for (int p = 0; p < PTS; ++p) {
    int a_s = __builtin_amdgcn_readfirstlane(assign_lds[p]); // block-uniform
    double xv = (double)fb[(size_t)p * DIM] * ib[p];
    switch (a_s) {
      CASE_ACC(0) CASE_ACC(1) CASE_ACC(2) CASE_ACC(3)
      CASE_ACC(4) CASE_ACC(5) CASE_ACC(6) CASE_ACC(7)
      CASE_ACC(8) CASE_ACC(9) CASE_ACC(10) CASE_ACC(11)
      CASE_ACC(12) CASE_ACC(13) CASE_ACC(14) CASE_ACC(15)
      CASE_ACC(16) CASE_ACC(17) CASE_ACC(18) CASE_ACC(19)
      CASE_ACC(20) CASE_ACC(21) CASE_ACC(22) CASE_ACC(23)
    }
  }

  double* ps = psums + ((size_t)(b * NCHUNK + ch) * NSLOT) * DIM + t;
#pragma unroll
  for (int k = 0; k < NSLOT; ++k) ps[(size_t)k * DIM] = acc[k];
  if (t == 0) {
    int* pc = pcnts + (b * NCHUNK + ch) * NSLOT;
#pragma unroll
    for (int k = 0; k < NSLOT; ++k) pc[k] = cnt[k];
  }
}

// ---------------- K2: reduce partials -> new centers (f64 + f32) + c_sq ----
__global__ __launch_bounds__(256) void k_update(const double* __restrict__ psums,
                                                const int* __restrict__ pcnts,
                                                double* __restrict__ centers,
                                                float* __restrict__ centers_f32,
                                                float* __restrict__ c_sq_f32) {
  __shared__ double red[4];
  int t = threadIdx.x, k = blockIdx.x, b = blockIdx.y;
  double s = 0.0;
#pragma unroll
  for (int ch = 0; ch < NCHUNK; ++ch)
    s += psums[((size_t)(b * NCHUNK + ch) * NSLOT + k) * DIM + t];
  int cnt = 0;
#pragma unroll
  for (int ch = 0; ch < NCHUNK; ++ch)
    cnt += pcnts[(b * NCHUNK + ch) * NSLOT + k];
  size_t ci = ((size_t)b * NSLOT + k) * DIM + t;
  double nc = (cnt > 0) ? (s / (double)cnt) : centers[ci];
  centers[ci] = nc;
  centers_f32[ci] = (float)nc;
  double sq = block_sum_256(nc * nc, red);
  if (t == 0) c_sq_f32[b * NSLOT + k] = (float)sq;
}

extern "C" void kernel_launch(void* const* d_in, const int* in_sizes, int n_in,
                              void* d_out, int out_size, void* d_ws, size_t ws_size,
                              hipStream_t stream) {
  (void)in_sizes; (void)n_in; (void)out_size; (void)ws_size;
  const float* feat = (const float*)d_in[0];
  float* out_centers = (float*)d_out;                           // (32,24,256)
  float* out_masks = out_centers + (size_t)BATCH * NSLOT * DIM; // (32,24,4096)

  // workspace layout (~28.3 MB)
  char* ws = (char*)d_ws;
  double* inv_norm    = (double*)ws; ws += (size_t)BATCH * NPTS * 8;                 // 1.0 MB
  double* centers     = (double*)ws; ws += (size_t)BATCH * NSLOT * DIM * 8;          // 1.5 MB
  double* psums       = (double*)ws; ws += (size_t)BATCH * NCHUNK * NSLOT * DIM * 8; // 25 MB
  float* centers_f32  = (float*)ws;  ws += (size_t)BATCH * NSLOT * DIM * 4;          // 0.75 MB
  float* c_sq_f32     = (float*)ws;  ws += (size_t)BATCH * NSLOT * 4;                // 3 KB
  int* pcnts          = (int*)ws;                                                    // 48 KB

  k_norm<<<BATCH * NPTS / 4, 256, 0, stream>>>(feat, inv_norm);
  k_init_centers<<<dim3(NSLOT, BATCH), 256, 0, stream>>>(feat, inv_norm, centers,
                                                         centers_f32, c_sq_f32);
  for (int it = 0; it < NITER; ++it) {
    k_iter<<<dim3(NCHUNK, BATCH), 256, 0, stream>>>(feat, inv_norm, centers, centers_f32,
                                                    c_sq_f32, psums, pcnts, nullptr, nullptr, 0);
    k_update<<<dim3(NSLOT, BATCH), 256, 0, stream>>>(psums, pcnts, centers,
                                                     centers_f32, c_sq_f32);
  }
  k_iter<<<dim3(NCHUNK, BATCH), 256, 0, stream>>>(feat, inv_norm, centers, centers_f32,
                                                  c_sq_f32, psums, pcnts, out_masks,
                                                  out_centers, 1);
}